// Round 10
// baseline (547.426 us; speedup 1.0000x reference)
//
#include <hip/hip_runtime.h>

// DissipativeRINN — fp16 MFMA, block-cooperative K-reduction, low-LDS-traffic.
// 256 blocks x 4 waves (256 thr); block = 8 batch rows (M-rows 0-7 of 16-tile).
// Wave w owns 2 N-tiles (w-elems 32w..32w+31): 8 MFMA/iter (4 indep 2-deep
// chains); A-fragment reads shared across both tiles (16 b128 reads/block).
// w stored K-PERMUTED: element 32w+16n+c at position 32w+2c+n, so each lane
// packs its two tanh outputs into one ds_write_b32 (16 writes/block).
// bD/bKU w-chunks built with the inverse permutation. One barrier/iter.

typedef _Float16 f16x8 __attribute__((ext_vector_type(8)));
typedef float f32x4 __attribute__((ext_vector_type(4)));

constexpr int B_TOT   = 2048;
constexpr int T_STEPS = 32;
constexpr int IN_D    = 16;
constexpr int ST_D    = 16;
constexpr int NL_D    = 128;
constexpr int OUT_D   = 8;
constexpr int H_D     = 64;
constexpr int OUT_C   = 17;
constexpr float DT_F  = 0.01f;
constexpr float SC    = 2.8853900817779268f;   // 2*log2(e)

constexpr int RB      = 8;                     // batch rows per block
constexpr int WBUF_SZ = 4096;                  // [16 rows][128 k] f16
constexpr int XY_OFF  = 2 * WBUF_SZ;           // xy tile [16][32] f16 (1 KB)
constexpr int LDS_SZ  = XY_OFF + 1024;

// storage permutation: position p holds w-element inv(p)
__device__ __forceinline__ int inv_perm(int p) {
    return 32 * (p >> 5) + 16 * (p & 1) + ((p & 31) >> 1);
}

__global__ __launch_bounds__(256, 1) void rinn_fpi(
    const float* __restrict__ obs, const float* __restrict__ x0,
    const float* __restrict__ A_T, const float* __restrict__ Bw_T,
    const float* __restrict__ By_T, const float* __restrict__ Cv_T,
    const float* __restrict__ Dvw_T, const float* __restrict__ Dvy_T,
    const float* __restrict__ Cu_T, const float* __restrict__ Duw_T,
    const float* __restrict__ Duy_T, float* __restrict__ out)
{
    __shared__ __align__(16) char lds[LDS_SZ];
    const int tid  = threadIdx.x;
    const int wid  = tid >> 6;                 // 0..3
    const int lane = tid & 63;
    const int g    = lane >> 4;
    const int c16  = lane & 15;
    const int b0   = blockIdx.x * RB;
    const f32x4 z4 = {0.f, 0.f, 0.f, 0.f};

    // ---- resident B fragments: 2 N-tiles per wave, k in STORAGE order ----
    f16x8 bD[4][2];
#pragma unroll
    for (int s = 0; s < 4; ++s)
#pragma unroll
        for (int n = 0; n < 2; ++n) {
            const int colO = 32 * wid + 16 * n + c16;   // output element
            f16x8 h;
#pragma unroll
            for (int j = 0; j < 8; ++j) {
                int in_e = inv_perm(s * 32 + g * 8 + j);
                h[j] = (_Float16)(SC * Dvw_T[in_e * NL_D + colO]);
            }
            bD[s][n] = h;
        }
    f16x8 bBias[2];                            // [Cv;Dvy] K=32 (x SC), std k
#pragma unroll
    for (int n = 0; n < 2; ++n) {
        const int colO = 32 * wid + 16 * n + c16;
        f16x8 h;
#pragma unroll
        for (int j = 0; j < 8; ++j) {
            int k = g * 8 + j;
            float v = (k < 16) ? Cv_T[k * NL_D + colO] : Dvy_T[(k - 16) * NL_D + colO];
            h[j] = (_Float16)(SC * v);
        }
        bBias[n] = h;
    }
    f16x8 bKU[5];                              // wave0: [A;By;Bw], wave1: [Cu;Duy;Duw]
    if (wid == 0) {
        f16x8 h;
#pragma unroll
        for (int j = 0; j < 8; ++j) {
            int k = g * 8 + j;
            h[j] = (_Float16)((k < 16) ? A_T[k * ST_D + c16] : By_T[(k - 16) * ST_D + c16]);
        }
        bKU[0] = h;
#pragma unroll
        for (int s = 0; s < 4; ++s) {
            f16x8 h2;
#pragma unroll
            for (int j = 0; j < 8; ++j) {
                int row = inv_perm(s * 32 + g * 8 + j);
                h2[j] = (_Float16)Bw_T[row * ST_D + c16];
            }
            bKU[1 + s] = h2;
        }
    } else if (wid == 1) {
        f16x8 h;
#pragma unroll
        for (int j = 0; j < 8; ++j) {
            int k = g * 8 + j;
            float v = (c16 < OUT_D)
                ? ((k < 16) ? Cu_T[k * OUT_D + c16] : Duy_T[(k - 16) * OUT_D + c16]) : 0.f;
            h[j] = (_Float16)v;
        }
        bKU[0] = h;
#pragma unroll
        for (int s = 0; s < 4; ++s) {
            f16x8 h2;
#pragma unroll
            for (int j = 0; j < 8; ++j) {
                int row = inv_perm(s * 32 + g * 8 + j);
                h2[j] = (_Float16)((c16 < OUT_D) ? Duw_T[row * OUT_D + c16] : 0.f);
            }
            bKU[1 + s] = h2;
        }
    }

    // ---- zero all LDS (pad rows must stay zero forever) ----
    for (int off = tid * 16; off < LDS_SZ; off += 256 * 16)
        *(f32x4*)(lds + off) = z4;
    __syncthreads();

    // ---- x state: wave 0 lanes g<2 hold rows 4g+j, col c16 ----
    f32x4 xb = z4, k1 = z4, k2 = z4, k3 = z4, k4 = z4;
    if (wid == 0 && g < 2) {
#pragma unroll
        for (int j = 0; j < 4; ++j) {
            int row = 4 * g + j;
            xb[j] = x0[(b0 + row) * ST_D + c16];
            *(_Float16*)(lds + XY_OFF + row * 64 + ((2 * c16) ^ ((row & 3) << 4))) =
                (_Float16)xb[j];
        }
    }

    auto ld_xy = [&]() -> f16x8 {
        return __builtin_bit_cast(f16x8,
            *(const f32x4*)(lds + XY_OFF + c16 * 64 + ((g * 16) ^ ((c16 & 3) << 4))));
    };
    // read: lane (g,c16) = A[row=c16][k=32s+8g..+7], slot=(4s+g)^c16 (bijective)
    auto ldA = [&](int buf, int s) -> f16x8 {
        return __builtin_bit_cast(f16x8,
            *(const f32x4*)(lds + buf * WBUF_SZ + c16 * 256 +
                            ((s * 64 + g * 16) ^ (c16 << 4))));
    };

    int cur = 0;

#pragma unroll 1
    for (int t = 0; t < T_STEPS; ++t) {
        // w_init = 0: zero rows 0-7 of w[cur] (2 KB, 8B/thread)
        *(long long*)(lds + cur * WBUF_SZ + tid * 8) = 0ll;
        // y rows 0-7 for this step (wave 2)
        if (wid == 2 && g < 2) {
#pragma unroll
            for (int j = 0; j < 4; ++j) {
                int row = 4 * g + j;
                float yv = obs[((b0 + row) * T_STEPS + t) * IN_D + c16];
                *(_Float16*)(lds + XY_OFF + row * 64 + ((32 + 2 * c16) ^ ((row & 3) << 4))) =
                    (_Float16)yv;
            }
        }
        __syncthreads();

#pragma unroll 1
        for (int st = 0; st < 4; ++st) {
            // bias for this stage's x (both N-tiles)
            f32x4 biasAcc[2];
            {
                f16x8 aXY = ld_xy();
#pragma unroll
                for (int n = 0; n < 2; ++n)
                    biasAcc[n] = __builtin_amdgcn_mfma_f32_16x16x32_f16(aXY, bBias[n], z4, 0, 0, 0);
            }
            const int niter = st ? 5 : 30;
#pragma unroll 1
            for (int it = 0; it < niter; ++it) {
                f16x8 a0 = ldA(cur, 0), a1 = ldA(cur, 1), a2 = ldA(cur, 2), a3 = ldA(cur, 3);
                // n=0 and n=1: four independent 2-deep chains
                f32x4 h00 = __builtin_amdgcn_mfma_f32_16x16x32_f16(a0, bD[0][0], biasAcc[0], 0, 0, 0);
                f32x4 h01 = __builtin_amdgcn_mfma_f32_16x16x32_f16(a0, bD[0][1], biasAcc[1], 0, 0, 0);
                f32x4 h10 = __builtin_amdgcn_mfma_f32_16x16x32_f16(a2, bD[2][0], z4, 0, 0, 0);
                f32x4 h11 = __builtin_amdgcn_mfma_f32_16x16x32_f16(a2, bD[2][1], z4, 0, 0, 0);
                h00 = __builtin_amdgcn_mfma_f32_16x16x32_f16(a1, bD[1][0], h00, 0, 0, 0);
                h01 = __builtin_amdgcn_mfma_f32_16x16x32_f16(a1, bD[1][1], h01, 0, 0, 0);
                h10 = __builtin_amdgcn_mfma_f32_16x16x32_f16(a3, bD[3][0], h10, 0, 0, 0);
                h11 = __builtin_amdgcn_mfma_f32_16x16x32_f16(a3, bD[3][1], h11, 0, 0, 0);
                f32x4 t0 = h00 + h10;
                f32x4 t1 = h01 + h11;
                // branchless tanh on all lanes; pack (n0,n1) -> b32
                if (g < 2) {
                    char* wb = lds + (cur ^ 1) * WBUF_SZ;
#pragma unroll
                    for (int j = 0; j < 4; ++j) {
                        float v0 = fmaf(-2.0f, __builtin_amdgcn_rcpf(1.0f + __builtin_amdgcn_exp2f(t0[j])), 1.0f);
                        float v1 = fmaf(-2.0f, __builtin_amdgcn_rcpf(1.0f + __builtin_amdgcn_exp2f(t1[j])), 1.0f);
                        int r = 4 * g + j;
                        int pk = __builtin_bit_cast(int, __builtin_amdgcn_cvt_pkrtz(v0, v1));
                        *(int*)(wb + r * 256 + (((4 * wid + (c16 >> 2)) ^ r) << 4) + 4 * (c16 & 3)) = pk;
                    }
                }
                __syncthreads();
                cur ^= 1;
            }
            // ---- epilogue: k (wave 0) / u (wave 1), K=160 over [xy | w] ----
            f32x4 acc = z4;
            if (wid < 2) {
                f16x8 aXY = ld_xy();
                f16x8 a0 = ldA(cur, 0), a1 = ldA(cur, 1), a2 = ldA(cur, 2), a3 = ldA(cur, 3);
                f32x4 e0 = __builtin_amdgcn_mfma_f32_16x16x32_f16(aXY, bKU[0], z4, 0, 0, 0);
                e0 = __builtin_amdgcn_mfma_f32_16x16x32_f16(a0, bKU[1], e0, 0, 0, 0);
                e0 = __builtin_amdgcn_mfma_f32_16x16x32_f16(a1, bKU[2], e0, 0, 0, 0);
                f32x4 e1 = __builtin_amdgcn_mfma_f32_16x16x32_f16(a2, bKU[3], z4, 0, 0, 0);
                e1 = __builtin_amdgcn_mfma_f32_16x16x32_f16(a3, bKU[4], e1, 0, 0, 0);
                acc = e0 + e1;
            }
            __syncthreads();                   // xy reads done before x update
            if (wid == 1 && st == 0 && c16 < OUT_D && g < 2) {
#pragma unroll
                for (int j = 0; j < 4; ++j)
                    out[((b0 + 4 * g + j) * T_STEPS + t) * OUT_C + c16] = acc[j];
            }
            if (wid == 0) {
                float xn[4];
                if (st == 0) {
                    k1 = acc;
#pragma unroll
                    for (int j = 0; j < 4; ++j) xn[j] = fmaf(0.5f * DT_F, k1[j], xb[j]);
                } else if (st == 1) {
                    k2 = acc;
#pragma unroll
                    for (int j = 0; j < 4; ++j) xn[j] = fmaf(0.5f * DT_F, k2[j], xb[j]);
                } else if (st == 2) {
                    k3 = acc;
#pragma unroll
                    for (int j = 0; j < 4; ++j) xn[j] = fmaf(DT_F, k3[j], xb[j]);
                } else {
                    k4 = acc;
#pragma unroll
                    for (int j = 0; j < 4; ++j) {
                        xb[j] = fmaf(DT_F / 6.0f,
                                     k1[j] + 2.0f * k2[j] + 2.0f * k3[j] + k4[j], xb[j]);
                        xn[j] = xb[j];
                    }
                }
                if (g < 2) {
#pragma unroll
                    for (int j = 0; j < 4; ++j) {
                        int row = 4 * g + j;
                        *(_Float16*)(lds + XY_OFF + row * 64 +
                                     ((2 * c16) ^ ((row & 3) << 4))) = (_Float16)xn[j];
                    }
                }
            }
            __syncthreads();                   // new x visible for next bias
        }
    }
}

// ---- value baseline MLP + log_std broadcast (unchanged) ----
__device__ __forceinline__ float fast_tanh(float a) {
    float e = __expf(2.0f * a);
    return 1.0f - 2.0f / (e + 1.0f);
}

__global__ __launch_bounds__(256) void mlp_kernel(
    const float* __restrict__ obs, const float* __restrict__ log_stds,
    const float* __restrict__ W1, const float* __restrict__ b1,
    const float* __restrict__ W2, const float* __restrict__ b2,
    const float* __restrict__ W3, const float* __restrict__ b3,
    float* __restrict__ out) {
    __shared__ float sW1[IN_D * H_D];
    __shared__ float sW2[H_D * H_D];
    __shared__ float sb1[H_D], sb2[H_D], sW3[H_D], sls[OUT_D];
    __shared__ float sb3;
    const int tid = threadIdx.x;
    for (int i = tid; i < IN_D * H_D; i += 256) sW1[i] = W1[i];
    for (int i = tid; i < H_D * H_D; i += 256) sW2[i] = W2[i];
    if (tid < H_D) { sb1[tid] = b1[tid]; sb2[tid] = b2[tid]; sW3[tid] = W3[tid]; }
    if (tid < OUT_D) sls[tid] = log_stds[tid];
    if (tid == 0) sb3 = b3[0];
    __syncthreads();

    const int bt = blockIdx.x * 256 + tid;
    if (bt >= B_TOT * T_STEPS) return;

    float o[IN_D];
#pragma unroll
    for (int i = 0; i < IN_D; ++i) o[i] = obs[bt * IN_D + i];

    float h1[H_D];
#pragma unroll
    for (int h = 0; h < H_D; ++h) {
        float a = sb1[h];
#pragma unroll
        for (int i = 0; i < IN_D; ++i) a = fmaf(o[i], sW1[i * H_D + h], a);
        h1[h] = fast_tanh(a);
    }
    float v = sb3;
#pragma unroll
    for (int h = 0; h < H_D; ++h) {
        float a = sb2[h];
#pragma unroll
        for (int i = 0; i < H_D; ++i) a = fmaf(h1[i], sW2[i * H_D + h], a);
        v = fmaf(fast_tanh(a), sW3[h], v);
    }

    float* o17 = out + bt * OUT_C;
#pragma unroll
    for (int q = 0; q < OUT_D; ++q) o17[OUT_D + q] = sls[q];
    o17[16] = v;
}

extern "C" void kernel_launch(void* const* d_in, const int* in_sizes, int n_in,
                              void* d_out, int out_size, void* d_ws, size_t ws_size,
                              hipStream_t stream) {
    const float* obs      = (const float*)d_in[0];
    const float* x0       = (const float*)d_in[1];
    const float* A_T      = (const float*)d_in[2];
    const float* Bw_T     = (const float*)d_in[3];
    const float* By_T     = (const float*)d_in[4];
    const float* Cv_T     = (const float*)d_in[5];
    const float* Dvw_T    = (const float*)d_in[6];
    const float* Dvy_T    = (const float*)d_in[7];
    const float* Cu_T     = (const float*)d_in[8];
    const float* Duw_T    = (const float*)d_in[9];
    const float* Duy_T    = (const float*)d_in[10];
    const float* log_stds = (const float*)d_in[11];
    const float* W1       = (const float*)d_in[12];
    const float* b1       = (const float*)d_in[13];
    const float* W2       = (const float*)d_in[14];
    const float* b2       = (const float*)d_in[15];
    const float* W3       = (const float*)d_in[16];
    const float* b3       = (const float*)d_in[17];
    float* out = (float*)d_out;

    rinn_fpi<<<dim3(B_TOT / RB), dim3(256), 0, stream>>>(
        obs, x0, A_T, Bw_T, By_T, Cv_T, Dvw_T, Dvy_T, Cu_T, Duw_T, Duy_T, out);
    mlp_kernel<<<dim3((B_TOT * T_STEPS + 255) / 256), dim3(256), 0, stream>>>(
        obs, log_stds, W1, b1, W2, b2, W3, b3, out);
}

// Round 11
// 427.491 us; speedup vs baseline: 1.2806x; 1.2806x over previous
//
#include <hip/hip_runtime.h>

// DissipativeRINN — TRANSPOSED fp16 MFMA: M = w-elements (128), N = batch rows (16).
// 128 blocks x 4 waves (256 thr); block = 16 batch rows; wave w owns M-tiles
// 2w, 2w+1 (8 MFMA/iter as 4 indep 2-deep chains).
// k-permutation p=32s+8g+j -> e=32s+16(j>>2)+4g+(j&3) makes each lane's C
// output exactly its next B-fragment: tanh stays in-register; the only
// exchange is 1 ds_write_b128 + barrier + 4 ds_read_b128 (double-buffered).
// Bias/k/u epilogues transposed the same way; k computed redundantly on all
// waves so the x-state stays lane-local (f32x4, no exchange ever).

typedef _Float16 f16x8 __attribute__((ext_vector_type(8)));
typedef float f32x4 __attribute__((ext_vector_type(4)));
typedef int i32x4 __attribute__((ext_vector_type(4)));

constexpr int B_TOT   = 2048;
constexpr int T_STEPS = 32;
constexpr int IN_D    = 16;
constexpr int ST_D    = 16;
constexpr int NL_D    = 128;
constexpr int OUT_D   = 8;
constexpr int H_D     = 64;
constexpr int OUT_C   = 17;
constexpr float DT_F  = 0.01f;
constexpr float SC    = 2.8853900817779268f;   // 2*log2(e)

// k-position p = 32s + 8g + j  <->  w-element e (bijective; bit-disjoint)
__device__ __forceinline__ int eperm(int s, int g, int j) {
    return 32 * s + 16 * (j >> 2) + 4 * g + (j & 3);
}

#define MFMA16(A, B, C) __builtin_amdgcn_mfma_f32_16x16x32_f16((A), (B), (C), 0, 0, 0)
#define PK(a, b) __builtin_bit_cast(int, __builtin_amdgcn_cvt_pkrtz((a), (b)))

__global__ __launch_bounds__(256, 1) void rinn_fpi(
    const float* __restrict__ obs, const float* __restrict__ x0,
    const float* __restrict__ A_T, const float* __restrict__ Bw_T,
    const float* __restrict__ By_T, const float* __restrict__ Cv_T,
    const float* __restrict__ Dvw_T, const float* __restrict__ Dvy_T,
    const float* __restrict__ Cu_T, const float* __restrict__ Duw_T,
    const float* __restrict__ Duy_T, float* __restrict__ out)
{
    __shared__ __align__(16) char xch[2][4][1024];   // [dbuf][chunk][lane*16B]
    const int tid  = threadIdx.x;
    const int wid  = tid >> 6;                 // owns M-tiles 2wid, 2wid+1; chunk wid
    const int lane = tid & 63;
    const int g    = lane >> 4;                // k-subgroup (A/B) / m-subgroup (C)
    const int r16  = lane & 15;                // A: m-row within tile; B/C: batch row
    const int row  = blockIdx.x * 16 + r16;    // this lane's batch row (B/C role)
    const f32x4 z4 = {0.f, 0.f, 0.f, 0.f};

    // ---- A fragments (M = w/out elements). Dvw_T[in][out], SC pre-scaled ----
    f16x8 aD[2][4];
#pragma unroll
    for (int n = 0; n < 2; ++n)
#pragma unroll
        for (int s = 0; s < 4; ++s) {
            f16x8 h;
#pragma unroll
            for (int j = 0; j < 8; ++j)
                h[j] = (_Float16)(SC * Dvw_T[eperm(s, g, j) * NL_D + 16 * (2 * wid + n) + r16]);
            aD[n][s] = h;
        }
    f16x8 aB[2];                               // [Cv;Dvy] over xy (K=32), x SC
#pragma unroll
    for (int n = 0; n < 2; ++n) {
        const int m = 16 * (2 * wid + n) + r16;
        f16x8 h;
#pragma unroll
        for (int j = 0; j < 8; ++j) {
            float v = (j < 4) ? Cv_T[(4 * g + j) * NL_D + m]
                              : Dvy_T[(4 * g + (j & 3)) * NL_D + m];
            h[j] = (_Float16)(SC * v);
        }
        aB[n] = h;
    }
    f16x8 aK[5];                               // k: [A;By] xy-chunk + Bw w-chunks
    {
        f16x8 h;
#pragma unroll
        for (int j = 0; j < 8; ++j)
            h[j] = (_Float16)((j < 4) ? A_T[(4 * g + j) * ST_D + r16]
                                      : By_T[(4 * g + (j & 3)) * ST_D + r16]);
        aK[0] = h;
#pragma unroll
        for (int s = 0; s < 4; ++s) {
            f16x8 h2;
#pragma unroll
            for (int j = 0; j < 8; ++j)
                h2[j] = (_Float16)Bw_T[eperm(s, g, j) * ST_D + r16];
            aK[1 + s] = h2;
        }
    }
    f16x8 aU[5];                               // u (wave 1 only; m'<8 real)
    if (wid == 1) {
        f16x8 h;
#pragma unroll
        for (int j = 0; j < 8; ++j) {
            float v = 0.f;
            if (r16 < OUT_D)
                v = (j < 4) ? Cu_T[(4 * g + j) * OUT_D + r16]
                            : Duy_T[(4 * g + (j & 3)) * OUT_D + r16];
            h[j] = (_Float16)v;
        }
        aU[0] = h;
#pragma unroll
        for (int s = 0; s < 4; ++s) {
            f16x8 h2;
#pragma unroll
            for (int j = 0; j < 8; ++j)
                h2[j] = (_Float16)((r16 < OUT_D) ? Duw_T[eperm(s, g, j) * OUT_D + r16] : 0.f);
            aU[1 + s] = h2;
        }
    } else {
#pragma unroll
        for (int s = 0; s < 5; ++s) aU[s] = __builtin_bit_cast(f16x8, z4);
    }

    // ---- lane-local state: x[4g+q] of batch row `row` ----
    f32x4 xb = *(const f32x4*)(x0 + row * ST_D + 4 * g);

    f16x8 pw0, pw1, pw2, pw3;                  // B-fragments of w (4 k-chunks)
    int cur = 0;
    char* const xbase = &xch[0][0][0];

    auto tanh4 = [&](f32x4 t) -> f32x4 {       // arg already 2*log2(e)*a
        f32x4 o;
#pragma unroll
        for (int q = 0; q < 4; ++q)
            o[q] = fmaf(-2.0f, __builtin_amdgcn_rcpf(1.0f + __builtin_amdgcn_exp2f(t[q])), 1.0f);
        return o;
    };

    auto fpi = [&](int niter, f32x4 bias0, f32x4 bias1) {
#pragma unroll 1
        for (int it = 0; it < niter; ++it) {
            // 4 independent 2-deep chains (tiles 2wid, 2wid+1 x k-halves)
            f32x4 c00 = MFMA16(aD[0][0], pw0, bias0);
            f32x4 c10 = MFMA16(aD[1][0], pw0, bias1);
            f32x4 c01 = MFMA16(aD[0][2], pw2, z4);
            f32x4 c11 = MFMA16(aD[1][2], pw2, z4);
            c00 = MFMA16(aD[0][1], pw1, c00);
            c10 = MFMA16(aD[1][1], pw1, c10);
            c01 = MFMA16(aD[0][3], pw3, c01);
            c11 = MFMA16(aD[1][3], pw3, c11);
            f32x4 v0 = tanh4(c00 + c01);       // tile 2wid  : elems 16*2wid + 4g+q
            f32x4 v1 = tanh4(c10 + c11);       // tile 2wid+1
            i32x4 own;                         // = B-chunk `wid` for this lane
            own[0] = PK(v0[0], v0[1]);
            own[1] = PK(v0[2], v0[3]);
            own[2] = PK(v1[0], v1[1]);
            own[3] = PK(v1[2], v1[3]);
            char* nb = xbase + (cur ^ 1) * 4096;
            *(i32x4*)(nb + wid * 1024 + lane * 16) = own;
            __syncthreads();
            pw0 = *(const f16x8*)(nb + 0 * 1024 + lane * 16);
            pw1 = *(const f16x8*)(nb + 1 * 1024 + lane * 16);
            pw2 = *(const f16x8*)(nb + 2 * 1024 + lane * 16);
            pw3 = *(const f16x8*)(nb + 3 * 1024 + lane * 16);
            cur ^= 1;
        }
    };

#pragma unroll 1
    for (int t = 0; t < T_STEPS; ++t) {
        f32x4 yb = *(const f32x4*)(obs + (row * T_STEPS + t) * IN_D + 4 * g);
        const int yw2 = PK(yb[0], yb[1]);
        const int yw3 = PK(yb[2], yb[3]);
        pw0 = pw1 = pw2 = pw3 = __builtin_bit_cast(f16x8, z4);   // w_init = 0
        f32x4 k1 = z4, k2 = z4, k3 = z4, k4 = z4;
        f32x4 xc = xb;

#pragma unroll
        for (int st = 0; st < 4; ++st) {
            i32x4 bxyw;
            bxyw[0] = PK(xc[0], xc[1]);
            bxyw[1] = PK(xc[2], xc[3]);
            bxyw[2] = yw2;
            bxyw[3] = yw3;
            f16x8 bXY = __builtin_bit_cast(f16x8, bxyw);
            f32x4 bias0 = MFMA16(aB[0], bXY, z4);
            f32x4 bias1 = MFMA16(aB[1], bXY, z4);
            fpi(st ? 5 : 30, bias0, bias1);
            // k epilogue — redundant on all waves keeps x replicated, no barrier
            f32x4 e0 = MFMA16(aK[0], bXY, z4);
            e0 = MFMA16(aK[1], pw0, e0);
            e0 = MFMA16(aK[2], pw1, e0);
            f32x4 e1 = MFMA16(aK[3], pw2, z4);
            e1 = MFMA16(aK[4], pw3, e1);
            f32x4 kc = e0 + e1;
            if (st == 0) {
                if (wid == 1) {                // u = x@Cu + w1@Duw + y@Duy
                    f32x4 u0 = MFMA16(aU[0], bXY, z4);
                    u0 = MFMA16(aU[1], pw0, u0);
                    u0 = MFMA16(aU[2], pw1, u0);
                    f32x4 u1 = MFMA16(aU[3], pw2, z4);
                    u1 = MFMA16(aU[4], pw3, u1);
                    f32x4 uc = u0 + u1;        // lane holds u[4g+q][row]
                    if (g < 2) {
                        float* op = out + (row * T_STEPS + t) * OUT_C + 4 * g;
                        op[0] = uc[0]; op[1] = uc[1]; op[2] = uc[2]; op[3] = uc[3];
                    }
                }
                k1 = kc;
#pragma unroll
                for (int q = 0; q < 4; ++q) xc[q] = fmaf(0.5f * DT_F, k1[q], xb[q]);
            } else if (st == 1) {
                k2 = kc;
#pragma unroll
                for (int q = 0; q < 4; ++q) xc[q] = fmaf(0.5f * DT_F, k2[q], xb[q]);
            } else if (st == 2) {
                k3 = kc;
#pragma unroll
                for (int q = 0; q < 4; ++q) xc[q] = fmaf(DT_F, k3[q], xb[q]);
            } else {
                k4 = kc;
#pragma unroll
                for (int q = 0; q < 4; ++q)
                    xb[q] = fmaf(DT_F / 6.0f,
                                 k1[q] + 2.0f * k2[q] + 2.0f * k3[q] + k4[q], xb[q]);
            }
        }
    }
}

// ---- value baseline MLP + log_std broadcast (unchanged, passes) ----
__device__ __forceinline__ float fast_tanh(float a) {
    float e = __expf(2.0f * a);
    return 1.0f - 2.0f / (e + 1.0f);
}

__global__ __launch_bounds__(256) void mlp_kernel(
    const float* __restrict__ obs, const float* __restrict__ log_stds,
    const float* __restrict__ W1, const float* __restrict__ b1,
    const float* __restrict__ W2, const float* __restrict__ b2,
    const float* __restrict__ W3, const float* __restrict__ b3,
    float* __restrict__ out) {
    __shared__ float sW1[IN_D * H_D];
    __shared__ float sW2[H_D * H_D];
    __shared__ float sb1[H_D], sb2[H_D], sW3[H_D], sls[OUT_D];
    __shared__ float sb3;
    const int tid = threadIdx.x;
    for (int i = tid; i < IN_D * H_D; i += 256) sW1[i] = W1[i];
    for (int i = tid; i < H_D * H_D; i += 256) sW2[i] = W2[i];
    if (tid < H_D) { sb1[tid] = b1[tid]; sb2[tid] = b2[tid]; sW3[tid] = W3[tid]; }
    if (tid < OUT_D) sls[tid] = log_stds[tid];
    if (tid == 0) sb3 = b3[0];
    __syncthreads();

    const int bt = blockIdx.x * 256 + tid;
    if (bt >= B_TOT * T_STEPS) return;

    float o[IN_D];
#pragma unroll
    for (int i = 0; i < IN_D; ++i) o[i] = obs[bt * IN_D + i];

    float h1[H_D];
#pragma unroll
    for (int h = 0; h < H_D; ++h) {
        float a = sb1[h];
#pragma unroll
        for (int i = 0; i < IN_D; ++i) a = fmaf(o[i], sW1[i * H_D + h], a);
        h1[h] = fast_tanh(a);
    }
    float v = sb3;
#pragma unroll
    for (int h = 0; h < H_D; ++h) {
        float a = sb2[h];
#pragma unroll
        for (int i = 0; i < H_D; ++i) a = fmaf(h1[i], sW2[i * H_D + h], a);
        v = fmaf(fast_tanh(a), sW3[h], v);
    }

    float* o17 = out + bt * OUT_C;
#pragma unroll
    for (int q = 0; q < OUT_D; ++q) o17[OUT_D + q] = sls[q];
    o17[16] = v;
}

extern "C" void kernel_launch(void* const* d_in, const int* in_sizes, int n_in,
                              void* d_out, int out_size, void* d_ws, size_t ws_size,
                              hipStream_t stream) {
    const float* obs      = (const float*)d_in[0];
    const float* x0       = (const float*)d_in[1];
    const float* A_T      = (const float*)d_in[2];
    const float* Bw_T     = (const float*)d_in[3];
    const float* By_T     = (const float*)d_in[4];
    const float* Cv_T     = (const float*)d_in[5];
    const float* Dvw_T    = (const float*)d_in[6];
    const float* Dvy_T    = (const float*)d_in[7];
    const float* Cu_T     = (const float*)d_in[8];
    const float* Duw_T    = (const float*)d_in[9];
    const float* Duy_T    = (const float*)d_in[10];
    const float* log_stds = (const float*)d_in[11];
    const float* W1       = (const float*)d_in[12];
    const float* b1       = (const float*)d_in[13];
    const float* W2       = (const float*)d_in[14];
    const float* b2       = (const float*)d_in[15];
    const float* W3       = (const float*)d_in[16];
    const float* b3       = (const float*)d_in[17];
    float* out = (float*)d_out;

    rinn_fpi<<<dim3(B_TOT / 16), dim3(256), 0, stream>>>(
        obs, x0, A_T, Bw_T, By_T, Cv_T, Dvw_T, Dvy_T, Cu_T, Duw_T, Duy_T, out);
    mlp_kernel<<<dim3((B_TOT * T_STEPS + 255) / 256), dim3(256), 0, stream>>>(
        obs, log_stds, W1, b1, W2, b2, W3, b3, out);
}